// Round 7
// baseline (213.008 us; speedup 1.0000x reference)
//
#include <hip/hip_runtime.h>
#include <hip/hip_bf16.h>
#include <math.h>

// Problem constants: B=2, Cin=Cout=32, D=H=W=32, 3x3x3 conv pad 1, 8 directions.
#define NB 2
#define NC 32
#define DD 32
#define VOL (DD*DD*DD)            // 32768
#define WDIR (NC*NC*27)           // 27648 floats per direction per gate
#define BUF_ELEMS (NB*VOL*NC)     // 2097152 elements per channel-last buffer (per dir)
#define WT_DIR (27*96*32)         // 82944 bf16 per direction (transposed weights)

typedef __attribute__((ext_vector_type(8))) short short8;   // 8 bf16 = 4 VGPRs
typedef __attribute__((ext_vector_type(4))) float f32x4;    // MFMA accumulator

__device__ __forceinline__ short f2bf(float v) {
    unsigned u = __float_as_uint(v);
    unsigned r = (u + 0x7fffu + ((u >> 16) & 1u)) >> 16;   // RNE
    return (short)r;
}
__device__ __forceinline__ float bf2f(short s) {
    return __uint_as_float(((unsigned)(unsigned short)s) << 16);
}
__device__ __forceinline__ float bf2f_lo(unsigned u) {
    return __uint_as_float(u << 16);
}
__device__ __forceinline__ float bf2f_hi(unsigned u) {
    return __uint_as_float(u & 0xffff0000u);
}
__device__ __forceinline__ unsigned pack2(float a, float b) {
    return ((unsigned)(unsigned short)f2bf(a)) | (((unsigned)(unsigned short)f2bf(b)) << 16);
}

// async global->LDS, 16 B per lane; lds dest = wave-uniform base + lane*16
__device__ __forceinline__ void async_copy16(const void* g, void* l) {
    __builtin_amdgcn_global_load_lds(
        (const __attribute__((address_space(1))) unsigned*)g,
        (__attribute__((address_space(3))) unsigned*)l, 16, 0, 0);
}

// ---------------------------------------------------------------------------
// Fused prep: blocks [0,2048) transpose x -> xT bf16 channel-last;
// blocks [2048,4640) transpose weights -> Wt bf16 [dir][tap][g*32+co][ci].
__global__ __launch_bounds__(256) void prep_xw(
    const float* __restrict__ x,
    const float* __restrict__ Wh, const float* __restrict__ Wz,
    const float* __restrict__ Ws,
    short* __restrict__ xT, short* __restrict__ Wt)
{
    __shared__ float tl[32][33];
    if (blockIdx.x < 2048) {
        const int blk = blockIdx.x;
        const int b = blk >> 10;
        const int i = (blk >> 5) & 31;
        const int j = blk & 31;

        const int k  = threadIdx.x & 31;
        const int cq = threadIdx.x >> 5;
        #pragma unroll
        for (int t = 0; t < 4; ++t) {
            const int ci = cq * 4 + t;
            tl[ci][k] = x[(((b*NC + ci)*DD + i)*DD + j)*DD + k];
        }
        __syncthreads();
        const int ci2 = threadIdx.x & 31;
        const int kq  = threadIdx.x >> 5;
        const int base = ((b*DD + i)*DD + j)*DD*NC;
        #pragma unroll
        for (int t = 0; t < 4; ++t) {
            const int kk = kq * 4 + t;
            xT[base + kk*NC + ci2] = f2bf(tl[ci2][kk]);
        }
    } else {
        const int idx = (blockIdx.x - 2048) * 256 + threadIdx.x;  // 663552 total
        if (idx >= 8*WT_DIR) return;
        const int ci  = idx & 31;
        const int n   = (idx >> 5) % 96;
        const int tap = (idx / (96*32)) % 27;
        const int dir = idx / WT_DIR;
        const int g   = n >> 5;
        const int co  = n & 31;
        const float* W = (g == 0) ? Wh : (g == 1) ? Wz : Ws;
        Wt[idx] = f2bf(W[dir*WDIR + (co*NC + ci)*27 + tap]);
    }
}

// ---------------------------------------------------------------------------
// Fused MFMA conv: ONE dir per block, 4096 blocks.
// Block = (b, i, 4 j's): M=128 voxels x N=96 (3 gates x 32 co).
// R6 ran M=256 / 65KB LDS -> 2 blocks/CU -> 2 waves/SIMD: per-g9 B-load
// vmcnt stall (~400 cyc) ~= per-wave MFMA issue (~350 cyc) -> MfmaUtil 38%.
// This round: As = 18x34x32 = 39KB -> 3 blocks/CU at launch_bounds(256,3)
// (3 waves/SIMD covers the B stall). Same one-barrier structure.
// MFMA called as (B, A, acc) so D = [n][voxel] -> packed 8B stores.
__global__ __launch_bounds__(256, 3) void conv_mfma(
    const short* __restrict__ xT, const short* __restrict__ Wt,
    const float* __restrict__ bh, const float* __restrict__ bz,
    const float* __restrict__ bs,
    short* __restrict__ bufh, short* __restrict__ bufz, short* __restrict__ bufs)
{
    __shared__ __align__(16) short As[18*34*32];     // 39,168 B

    const int tid  = threadIdx.x;
    const int lane = tid & 63;
    const int wave = tid >> 6;
    const int mh   = wave & 1;    // m-half: 2 j-rows each (M=128 -> 8 tiles of 16)
    const int nh   = wave >> 1;   // n-half: 3 n-tiles each (N=96 -> 6 tiles)
    const int lr   = lane & 15;
    const int lq   = lane >> 4;

    const int blk = blockIdx.x;   // 4096 = dir(8) x b(2) x i(32) x jq(8)
    const int j0  = (blk & 7) * 4;
    const int i   = (blk >> 3) & 31;
    const int b   = (blk >> 8) & 1;
    const int dir = blk >> 9;

    // ---- zero the k-edge slots (kvr=0 and kvr=33) of all 18 rows ----
    if (tid < 144) {
        const int row = tid >> 3;
        const int e   = tid & 7;
        const int off = row*2176 + (e < 4 ? e*16 : 2112 + (e - 4)*16);
        *(short8*)((char*)As + off) = short8{};
    }
    // ---- stage A interior (async) / zero invalid halo rows; ONCE per block ----
    for (int t = wave; t < 36; t += 4) {            // 18 rows x 2 halves of 1 KB
        const int row  = t >> 1;
        const int half = t & 1;
        const int rr = row / 6, jc = row - rr*6;
        const int ii = i + rr - 1, jj = j0 + jc - 1;
        char* ldst = (char*)As + row*2176 + 64 + half*1024 + lane*16;
        if ((unsigned)ii < 32u && (unsigned)jj < 32u) {
            const char* g = (const char*)(xT + ((b*DD + ii)*DD + jj)*DD*NC)
                            + half*1024 + lane*16;
            async_copy16(g, ldst);
        } else {
            *(short8*)ldst = short8{};
        }
    }
    __syncthreads();   // the ONLY barrier

    const int nbase = nh*48;
    const short* __restrict__ Wd = Wt + dir*WT_DIR;

    // ---- init accumulators with bias (row = n after operand swap) ----
    f32x4 acc[4][3];
    #pragma unroll
    for (int nt = 0; nt < 3; ++nt) {
        #pragma unroll
        for (int r = 0; r < 4; ++r) {
            const int n = nbase + nt*16 + lq*4 + r;
            const int gg = n >> 5, co = n & 31;
            const float bv = (gg == 0) ? bh[dir*NC + co]
                           : (gg == 1) ? bz[dir*NC + co] : bs[dir*NC + co];
            #pragma unroll
            for (int mt = 0; mt < 4; ++mt) acc[mt][nt][r] = bv;
        }
    }

    // ---- main loop: 9 (ri,rj) groups x 3 rk taps; B single-buffered ----
    #pragma unroll
    for (int g9 = 0; g9 < 9; ++g9) {
        short8 bfr[3][3];   // [rk][nt], 36 VGPRs
        #pragma unroll
        for (int rk = 0; rk < 3; ++rk)
            #pragma unroll
            for (int nt = 0; nt < 3; ++nt)
                bfr[rk][nt] = *(const short8*)
                    &Wd[((g9*3 + rk)*96 + nbase + nt*16 + lr)*32 + lq*8];

        const int ri = g9 / 3;
        const int rj = g9 - 3*ri;
        const int rowb = (ri*6 + mh*2 + rj) * 1088;

        #pragma unroll
        for (int rk = 0; rk < 3; ++rk) {
            short8 afr[4];
            #pragma unroll
            for (int mt = 0; mt < 4; ++mt) {
                const int jd  = mt >> 1;
                const int kvr = (mt & 1)*16 + lr + rk;
                afr[mt] = *(const short8*)&As[rowb + jd*1088 + kvr*32 + lq*8];
            }
            #pragma unroll
            for (int mt = 0; mt < 4; ++mt)
                #pragma unroll
                for (int nt = 0; nt < 3; ++nt)
                    acc[mt][nt] = __builtin_amdgcn_mfma_f32_16x16x32_bf16(
                        bfr[rk][nt], afr[mt], acc[mt][nt], 0, 0, 0);
        }
    }

    // ---- epilogue: D row = n (lq*4+r), col = voxel (lr); packed 8B stores ----
    #pragma unroll
    for (int nt = 0; nt < 3; ++nt) {
        const int n0 = nbase + nt*16 + lq*4;
        const int gg = n0 >> 5;
        const int co = n0 & 31;
        short* __restrict__ dst = ((gg == 0) ? bufh : (gg == 1) ? bufz : bufs)
                                  + (size_t)dir * BUF_ELEMS;
        #pragma unroll
        for (int mt = 0; mt < 4; ++mt) {
            const int jd = mt >> 1;
            const int kv = (mt & 1)*16 + lr;
            float v0 = acc[mt][nt][0], v1 = acc[mt][nt][1];
            float v2 = acc[mt][nt][2], v3 = acc[mt][nt][3];
            if (gg != 0) {
                v0 = 1.0f/(1.0f + __expf(-v0)); v1 = 1.0f/(1.0f + __expf(-v1));
                v2 = 1.0f/(1.0f + __expf(-v2)); v3 = 1.0f/(1.0f + __expf(-v3));
            }
            uint2 pk = { pack2(v0, v1), pack2(v2, v3) };
            *(uint2*)&dst[((((b*DD + i)*DD + (j0 + mh*2 + jd))*DD + kv)*NC) + co] = pk;
        }
    }
}

// ---------------------------------------------------------------------------
// Fused diagonal GRU scan: ALL 8 directions in one dispatch (blockIdx.z = dir).
// Writes contrib = o*s (bf16) to the separate cont buffer. 4 channels per lane
// via uint2: 8 lanes per chain.
__global__ __launch_bounds__(256) void gru_scan(
    const short* __restrict__ bufh, const short* __restrict__ bufz,
    const short* __restrict__ bufs, short* __restrict__ cont,
    const float* __restrict__ h0)
{
    const int dir = blockIdx.z;
    const int di = (dir & 4) ? 1 : -1;
    const int dj = (dir & 2) ? 1 : -1;
    const int dk = (dir & 1) ? 1 : -1;
    const size_t doff = (size_t)dir * BUF_ELEMS;
    const short* __restrict__ bh_ = bufh + doff;
    const short* __restrict__ bz_ = bufz + doff;
    const short* __restrict__ bs_ = bufs + doff;
    short* __restrict__ ct_ = cont + doff;

    const int c8   = threadIdx.x & 7;      // channel quad: channels 4*c8..4*c8+3
    const int slot = threadIdx.x >> 3;     // 32 chains per block
    const int cid  = blockIdx.x * 32 + slot;
    if (cid >= 2977) return;
    const int b = blockIdx.y;

    int ic, jc, kc;
    if (cid < 1024)      { ic = 0;             jc = cid >> 5;      kc = cid & 31; }
    else if (cid < 2016) { int t = cid - 1024; ic = 1 + (t >> 5);  jc = 0; kc = t & 31; }
    else                 { int t = cid - 2016; int q = t / 31;
                           ic = 1 + q;         jc = 1 + (t - q*31); kc = 0; }

    int mx = ic > jc ? ic : jc; if (kc > mx) mx = kc;
    const int L  = 32 - mx;
    const int i0 = (di > 0) ? ic : 31 - ic;
    const int j0 = (dj > 0) ? jc : 31 - jc;
    const int k0 = (dk > 0) ? kc : 31 - kc;
    const int step = di*(DD*DD*NC) + dj*(DD*NC) + dk*NC;

    int p = b*(VOL*NC) + i0*(DD*DD*NC) + j0*(DD*NC) + k0*NC + c8*4;
    float p0 = h0[dir*NC + c8*4 + 0];
    float p1 = h0[dir*NC + c8*4 + 1];
    float p2 = h0[dir*NC + c8*4 + 2];
    float p3 = h0[dir*NC + c8*4 + 3];

    for (int s = 0; s < L; ++s) {
        const uint2 uz = *(const uint2*)&bz_[p];
        const uint2 uh = *(const uint2*)&bh_[p];
        const uint2 us = *(const uint2*)&bs_[p];

        const float z0 = bf2f_lo(uz.x), z1 = bf2f_hi(uz.x);
        const float z2 = bf2f_lo(uz.y), z3 = bf2f_hi(uz.y);
        const float h0v = bf2f_lo(uh.x), h1v = bf2f_hi(uh.x);
        const float h2v = bf2f_lo(uh.y), h3v = bf2f_hi(uh.y);
        const float s0 = bf2f_lo(us.x), s1 = bf2f_hi(us.x);
        const float s2 = bf2f_lo(us.y), s3 = bf2f_hi(us.y);

        const float o0 = z0*h0v + (1.0f - z0)*p0;
        const float o1 = z1*h1v + (1.0f - z1)*p1;
        const float o2 = z2*h2v + (1.0f - z2)*p2;
        const float o3 = z3*h3v + (1.0f - z3)*p3;

        uint2 pk = { pack2(o0*s0, o1*s1), pack2(o2*s2, o3*s3) };
        *(uint2*)&ct_[p] = pk;

        p0 = o0; p1 = o1; p2 = o2; p3 = o3;
        p += step;
    }
}

// ---------------------------------------------------------------------------
// Sum 8 dir contribs (bf16, channel-last) and transpose -> out (b,c,i,j,k) fp32.
__global__ __launch_bounds__(256) void transpose_out(
    const short* __restrict__ contrib, float* __restrict__ out)
{
    __shared__ float tl[32][33];
    const int blk = blockIdx.x;
    const int b = blk >> 10;
    const int i = (blk >> 5) & 31;
    const int j = blk & 31;

    const int c  = threadIdx.x & 31;
    const int kq = threadIdx.x >> 5;
    const int base = ((b*DD + i)*DD + j)*DD*NC;
    #pragma unroll
    for (int t = 0; t < 4; ++t) {
        const int k = kq*4 + t;
        float s = 0.0f;
        #pragma unroll
        for (int d = 0; d < 8; ++d)
            s += bf2f(contrib[(size_t)d*BUF_ELEMS + base + k*NC + c]);
        tl[k][c] = s;
    }
    __syncthreads();

    const int k2 = threadIdx.x & 31;
    const int cq = threadIdx.x >> 5;
    const int obase = b*(NC*VOL) + i*(DD*DD) + j*DD;
    #pragma unroll
    for (int t = 0; t < 4; ++t) {
        const int co = cq*4 + t;
        out[obase + co*VOL + k2] = tl[k2][co];
    }
}

// ---------------------------------------------------------------------------
extern "C" void kernel_launch(void* const* d_in, const int* in_sizes, int n_in,
                              void* d_out, int out_size, void* d_ws, size_t ws_size,
                              hipStream_t stream)
{
    const float* x  = (const float*)d_in[0];
    const float* Wh = (const float*)d_in[1];
    const float* bh = (const float*)d_in[2];
    const float* Wz = (const float*)d_in[3];
    const float* bz = (const float*)d_in[4];
    const float* Ws = (const float*)d_in[5];
    const float* bs = (const float*)d_in[6];
    const float* h0 = (const float*)d_in[7];
    float* out = (float*)d_out;

    // Workspace layout (~140 MB total):
    short* bufh = (short*)d_ws;                          // 8 dirs x 4 MB bf16
    short* bufz = bufh + 8*(size_t)BUF_ELEMS;            // 33.5 MB
    short* bufs = bufz + 8*(size_t)BUF_ELEMS;            // 33.5 MB
    short* xT   = bufs + 8*(size_t)BUF_ELEMS;            // 4 MB bf16 channel-last x
    short* Wt   = xT + BUF_ELEMS;                        // 1.33 MB bf16 weights (8 dirs)
    short* cont = Wt + 8*(size_t)WT_DIR;                 // 8 dirs x 4 MB bf16 contribs

    // Fused input/weight transposes (one dispatch).
    prep_xw<<<2048 + (8*WT_DIR + 255)/256, 256, 0, stream>>>(x, Wh, Wz, Ws, xT, Wt);

    // One conv dispatch for all 8 directions (one dir per block, M=128 tiles).
    conv_mfma<<<8*NB*DD*8, 256, 0, stream>>>(xT, Wt, bh, bz, bs, bufh, bufz, bufs);

    // One fused scan dispatch for all 8 directions (contribs into cont).
    gru_scan<<<dim3((2977 + 31)/32, NB, 8), 256, 0, stream>>>(bufh, bufz, bufs, cont, h0);

    // Sum dirs + transpose.
    transpose_out<<<NB*DD*DD, 256, 0, stream>>>(cont, out);
}

// Round 8
// 199.962 us; speedup vs baseline: 1.0652x; 1.0652x over previous
//
#include <hip/hip_runtime.h>
#include <hip/hip_bf16.h>
#include <math.h>

// Problem constants: B=2, Cin=Cout=32, D=H=W=32, 3x3x3 conv pad 1, 8 directions.
#define NB 2
#define NC 32
#define DD 32
#define VOL (DD*DD*DD)            // 32768
#define WDIR (NC*NC*27)           // 27648 floats per direction per gate
#define BUF_ELEMS (NB*VOL*NC)     // 2097152 elements per channel-last buffer (per dir)
#define WT_DIR (27*96*32)         // 82944 bf16 per direction (transposed weights)

typedef __attribute__((ext_vector_type(8))) short short8;   // 8 bf16 = 4 VGPRs
typedef __attribute__((ext_vector_type(4))) float f32x4;    // MFMA accumulator

__device__ __forceinline__ short f2bf(float v) {
    unsigned u = __float_as_uint(v);
    unsigned r = (u + 0x7fffu + ((u >> 16) & 1u)) >> 16;   // RNE
    return (short)r;
}
__device__ __forceinline__ float bf2f(short s) {
    return __uint_as_float(((unsigned)(unsigned short)s) << 16);
}
__device__ __forceinline__ float bf2f_lo(unsigned u) {
    return __uint_as_float(u << 16);
}
__device__ __forceinline__ float bf2f_hi(unsigned u) {
    return __uint_as_float(u & 0xffff0000u);
}
__device__ __forceinline__ unsigned pack2(float a, float b) {
    return ((unsigned)(unsigned short)f2bf(a)) | (((unsigned)(unsigned short)f2bf(b)) << 16);
}

// async global->LDS, 16 B per lane; lds dest = wave-uniform base + lane*16
__device__ __forceinline__ void async_copy16(const void* g, void* l) {
    __builtin_amdgcn_global_load_lds(
        (const __attribute__((address_space(1))) unsigned*)g,
        (__attribute__((address_space(3))) unsigned*)l, 16, 0, 0);
}

// ---------------------------------------------------------------------------
// Fused prep: blocks [0,2048) transpose x -> xT bf16 channel-last;
// blocks [2048,4640) transpose weights -> Wt bf16 [dir][tap][g*32+co][ci].
__global__ __launch_bounds__(256) void prep_xw(
    const float* __restrict__ x,
    const float* __restrict__ Wh, const float* __restrict__ Wz,
    const float* __restrict__ Ws,
    short* __restrict__ xT, short* __restrict__ Wt)
{
    __shared__ float tl[32][33];
    if (blockIdx.x < 2048) {
        const int blk = blockIdx.x;
        const int b = blk >> 10;
        const int i = (blk >> 5) & 31;
        const int j = blk & 31;

        const int k  = threadIdx.x & 31;
        const int cq = threadIdx.x >> 5;
        #pragma unroll
        for (int t = 0; t < 4; ++t) {
            const int ci = cq * 4 + t;
            tl[ci][k] = x[(((b*NC + ci)*DD + i)*DD + j)*DD + k];
        }
        __syncthreads();
        const int ci2 = threadIdx.x & 31;
        const int kq  = threadIdx.x >> 5;
        const int base = ((b*DD + i)*DD + j)*DD*NC;
        #pragma unroll
        for (int t = 0; t < 4; ++t) {
            const int kk = kq * 4 + t;
            xT[base + kk*NC + ci2] = f2bf(tl[ci2][kk]);
        }
    } else {
        const int idx = (blockIdx.x - 2048) * 256 + threadIdx.x;  // 663552 total
        if (idx >= 8*WT_DIR) return;
        const int ci  = idx & 31;
        const int n   = (idx >> 5) % 96;
        const int tap = (idx / (96*32)) % 27;
        const int dir = idx / WT_DIR;
        const int g   = n >> 5;
        const int co  = n & 31;
        const float* W = (g == 0) ? Wh : (g == 1) ? Wz : Ws;
        Wt[idx] = f2bf(W[dir*WDIR + (co*NC + ci)*27 + tap]);
    }
}

// ---------------------------------------------------------------------------
// Fused MFMA conv: ONE dir per block (dir from blockIdx), 2048 blocks total.
// Block = (b, i, 8 j's): M=256 voxels x N=96 (3 gates x 32 co).  R6-validated
// geometry (97.7us, MfmaUtil 38%).  NEW this round: register DOUBLE-BUFFERED
// B-frags -- group g+1's 9 loads issue before group g's MFMA burst, so the
// per-group vmcnt(0) stall (~300 cyc L2) overlaps 72 MFMAs.  Reg budget at
// 2 blocks/CU: ~140 VGPR + 96 AGPR = 236 <= 256 (R4's spill came from its
// 4-dir loop liveness, not double-buffering itself).
__global__ __launch_bounds__(256, 2) void conv_mfma(
    const short* __restrict__ xT, const short* __restrict__ Wt,
    const float* __restrict__ bh, const float* __restrict__ bz,
    const float* __restrict__ bs,
    short* __restrict__ bufh, short* __restrict__ bufz, short* __restrict__ bufs)
{
    __shared__ __align__(16) short As[30*34*32];     // 65,280 B

    const int tid  = threadIdx.x;
    const int lane = tid & 63;
    const int wave = tid >> 6;
    const int mh   = wave & 1;    // m-half: 8 m-tiles each (M=256 -> 16 tiles)
    const int nh   = wave >> 1;   // n-half: 3 n-tiles each (N=96 -> 6 tiles)
    const int lr   = lane & 15;
    const int lq   = lane >> 4;

    const int blk = blockIdx.x;   // 2048 = dir(8) x b(2) x i(32) x jq(4)
    const int j0  = (blk & 3) * 8;
    const int i   = (blk >> 2) & 31;
    const int b   = (blk >> 7) & 1;
    const int dir = blk >> 8;

    // ---- zero the k-edge slots (kvr=0 and kvr=33) of all 30 rows ----
    if (tid < 240) {
        const int row = tid >> 3;
        const int e   = tid & 7;
        const int off = row*2176 + (e < 4 ? e*16 : 2112 + (e - 4)*16);
        *(short8*)((char*)As + off) = short8{};
    }
    // ---- stage A interior (async) / zero invalid halo rows; ONCE per block ----
    for (int t = wave; t < 60; t += 4) {            // 30 rows x 2 halves of 1 KB
        const int row  = t >> 1;
        const int half = t & 1;
        const int rr = row / 10, jc = row - rr*10;
        const int ii = i + rr - 1, jj = j0 + jc - 1;
        char* ldst = (char*)As + row*2176 + 64 + half*1024 + lane*16;
        if ((unsigned)ii < 32u && (unsigned)jj < 32u) {
            const char* g = (const char*)(xT + ((b*DD + ii)*DD + jj)*DD*NC)
                            + half*1024 + lane*16;
            async_copy16(g, ldst);
        } else {
            *(short8*)ldst = short8{};
        }
    }
    __syncthreads();   // the ONLY barrier

    const int nbase = nh*48;
    // lane-fixed B base: element ((g*3+rk)*96 + nbase + nt*16 + lr)*32 + lq*8
    //                  = Wb + (g*3+rk)*3072 + nt*512
    const short* __restrict__ Wb = Wt + dir*WT_DIR + (nbase + lr)*32 + lq*8;

    // ---- init accumulators with bias (row = n after operand swap) ----
    f32x4 acc[8][3];
    #pragma unroll
    for (int nt = 0; nt < 3; ++nt) {
        #pragma unroll
        for (int r = 0; r < 4; ++r) {
            const int n = nbase + nt*16 + lq*4 + r;
            const int gg = n >> 5, co = n & 31;
            const float bv = (gg == 0) ? bh[dir*NC + co]
                           : (gg == 1) ? bz[dir*NC + co] : bs[dir*NC + co];
            #pragma unroll
            for (int mt = 0; mt < 8; ++mt) acc[mt][nt][r] = bv;
        }
    }

    // ---- main loop: 9 (ri,rj) groups x 3 rk taps; B register double-buffer ----
    short8 bfr[2][3][3];   // [buf][rk][nt]
    #pragma unroll
    for (int rk = 0; rk < 3; ++rk)
        #pragma unroll
        for (int nt = 0; nt < 3; ++nt)
            bfr[0][rk][nt] = *(const short8*)&Wb[rk*3072 + nt*512];

    #pragma unroll
    for (int g9 = 0; g9 < 9; ++g9) {
        const int cur = g9 & 1;
        if (g9 < 8) {
            #pragma unroll
            for (int rk = 0; rk < 3; ++rk)
                #pragma unroll
                for (int nt = 0; nt < 3; ++nt)
                    bfr[cur ^ 1][rk][nt] =
                        *(const short8*)&Wb[((g9 + 1)*3 + rk)*3072 + nt*512];
        }
        const int ri = g9 / 3;
        const int rj = g9 - 3*ri;
        const int rowb = (ri*10 + mh*4 + rj) * 1088;

        #pragma unroll
        for (int rk = 0; rk < 3; ++rk) {
            short8 afr[8];
            #pragma unroll
            for (int mt = 0; mt < 8; ++mt) {
                const int jd  = mt >> 1;
                const int kvr = (mt & 1)*16 + lr + rk;
                afr[mt] = *(const short8*)&As[rowb + jd*1088 + kvr*32 + lq*8];
            }
            #pragma unroll
            for (int mt = 0; mt < 8; ++mt)
                #pragma unroll
                for (int nt = 0; nt < 3; ++nt)
                    acc[mt][nt] = __builtin_amdgcn_mfma_f32_16x16x32_bf16(
                        bfr[cur][rk][nt], afr[mt], acc[mt][nt], 0, 0, 0);
        }
    }

    // ---- epilogue: D row = n (lq*4+r), col = voxel (lr); packed 8B stores ----
    #pragma unroll
    for (int nt = 0; nt < 3; ++nt) {
        const int n0 = nbase + nt*16 + lq*4;
        const int gg = n0 >> 5;
        const int co = n0 & 31;
        short* __restrict__ dst = ((gg == 0) ? bufh : (gg == 1) ? bufz : bufs)
                                  + (size_t)dir * BUF_ELEMS;
        #pragma unroll
        for (int mt = 0; mt < 8; ++mt) {
            const int jd = mt >> 1;
            const int kv = (mt & 1)*16 + lr;
            float v0 = acc[mt][nt][0], v1 = acc[mt][nt][1];
            float v2 = acc[mt][nt][2], v3 = acc[mt][nt][3];
            if (gg != 0) {
                v0 = 1.0f/(1.0f + __expf(-v0)); v1 = 1.0f/(1.0f + __expf(-v1));
                v2 = 1.0f/(1.0f + __expf(-v2)); v3 = 1.0f/(1.0f + __expf(-v3));
            }
            uint2 pk = { pack2(v0, v1), pack2(v2, v3) };
            *(uint2*)&dst[((((b*DD + i)*DD + (j0 + mh*4 + jd))*DD + kv)*NC) + co] = pk;
        }
    }
}

// ---------------------------------------------------------------------------
// Fused diagonal GRU scan: ALL 8 directions in one dispatch (blockIdx.z = dir).
// Writes contrib = o*s (bf16) to the separate cont buffer. 4 channels per lane
// via uint2: 8 lanes per chain.
__global__ __launch_bounds__(256) void gru_scan(
    const short* __restrict__ bufh, const short* __restrict__ bufz,
    const short* __restrict__ bufs, short* __restrict__ cont,
    const float* __restrict__ h0)
{
    const int dir = blockIdx.z;
    const int di = (dir & 4) ? 1 : -1;
    const int dj = (dir & 2) ? 1 : -1;
    const int dk = (dir & 1) ? 1 : -1;
    const size_t doff = (size_t)dir * BUF_ELEMS;
    const short* __restrict__ bh_ = bufh + doff;
    const short* __restrict__ bz_ = bufz + doff;
    const short* __restrict__ bs_ = bufs + doff;
    short* __restrict__ ct_ = cont + doff;

    const int c8   = threadIdx.x & 7;      // channel quad: channels 4*c8..4*c8+3
    const int slot = threadIdx.x >> 3;     // 32 chains per block
    const int cid  = blockIdx.x * 32 + slot;
    if (cid >= 2977) return;
    const int b = blockIdx.y;

    int ic, jc, kc;
    if (cid < 1024)      { ic = 0;             jc = cid >> 5;      kc = cid & 31; }
    else if (cid < 2016) { int t = cid - 1024; ic = 1 + (t >> 5);  jc = 0; kc = t & 31; }
    else                 { int t = cid - 2016; int q = t / 31;
                           ic = 1 + q;         jc = 1 + (t - q*31); kc = 0; }

    int mx = ic > jc ? ic : jc; if (kc > mx) mx = kc;
    const int L  = 32 - mx;
    const int i0 = (di > 0) ? ic : 31 - ic;
    const int j0 = (dj > 0) ? jc : 31 - jc;
    const int k0 = (dk > 0) ? kc : 31 - kc;
    const int step = di*(DD*DD*NC) + dj*(DD*NC) + dk*NC;

    int p = b*(VOL*NC) + i0*(DD*DD*NC) + j0*(DD*NC) + k0*NC + c8*4;
    float p0 = h0[dir*NC + c8*4 + 0];
    float p1 = h0[dir*NC + c8*4 + 1];
    float p2 = h0[dir*NC + c8*4 + 2];
    float p3 = h0[dir*NC + c8*4 + 3];

    for (int s = 0; s < L; ++s) {
        const uint2 uz = *(const uint2*)&bz_[p];
        const uint2 uh = *(const uint2*)&bh_[p];
        const uint2 us = *(const uint2*)&bs_[p];

        const float z0 = bf2f_lo(uz.x), z1 = bf2f_hi(uz.x);
        const float z2 = bf2f_lo(uz.y), z3 = bf2f_hi(uz.y);
        const float h0v = bf2f_lo(uh.x), h1v = bf2f_hi(uh.x);
        const float h2v = bf2f_lo(uh.y), h3v = bf2f_hi(uh.y);
        const float s0 = bf2f_lo(us.x), s1 = bf2f_hi(us.x);
        const float s2 = bf2f_lo(us.y), s3 = bf2f_hi(us.y);

        const float o0 = z0*h0v + (1.0f - z0)*p0;
        const float o1 = z1*h1v + (1.0f - z1)*p1;
        const float o2 = z2*h2v + (1.0f - z2)*p2;
        const float o3 = z3*h3v + (1.0f - z3)*p3;

        uint2 pk = { pack2(o0*s0, o1*s1), pack2(o2*s2, o3*s3) };
        *(uint2*)&ct_[p] = pk;

        p0 = o0; p1 = o1; p2 = o2; p3 = o3;
        p += step;
    }
}

// ---------------------------------------------------------------------------
// Sum 8 dir contribs (bf16, channel-last) and transpose -> out (b,c,i,j,k) fp32.
__global__ __launch_bounds__(256) void transpose_out(
    const short* __restrict__ contrib, float* __restrict__ out)
{
    __shared__ float tl[32][33];
    const int blk = blockIdx.x;
    const int b = blk >> 10;
    const int i = (blk >> 5) & 31;
    const int j = blk & 31;

    const int c  = threadIdx.x & 31;
    const int kq = threadIdx.x >> 5;
    const int base = ((b*DD + i)*DD + j)*DD*NC;
    #pragma unroll
    for (int t = 0; t < 4; ++t) {
        const int k = kq*4 + t;
        float s = 0.0f;
        #pragma unroll
        for (int d = 0; d < 8; ++d)
            s += bf2f(contrib[(size_t)d*BUF_ELEMS + base + k*NC + c]);
        tl[k][c] = s;
    }
    __syncthreads();

    const int k2 = threadIdx.x & 31;
    const int cq = threadIdx.x >> 5;
    const int obase = b*(NC*VOL) + i*(DD*DD) + j*DD;
    #pragma unroll
    for (int t = 0; t < 4; ++t) {
        const int co = cq*4 + t;
        out[obase + co*VOL + k2] = tl[k2][co];
    }
}

// ---------------------------------------------------------------------------
extern "C" void kernel_launch(void* const* d_in, const int* in_sizes, int n_in,
                              void* d_out, int out_size, void* d_ws, size_t ws_size,
                              hipStream_t stream)
{
    const float* x  = (const float*)d_in[0];
    const float* Wh = (const float*)d_in[1];
    const float* bh = (const float*)d_in[2];
    const float* Wz = (const float*)d_in[3];
    const float* bz = (const float*)d_in[4];
    const float* Ws = (const float*)d_in[5];
    const float* bs = (const float*)d_in[6];
    const float* h0 = (const float*)d_in[7];
    float* out = (float*)d_out;

    // Workspace layout (~140 MB total):
    short* bufh = (short*)d_ws;                          // 8 dirs x 4 MB bf16
    short* bufz = bufh + 8*(size_t)BUF_ELEMS;            // 33.5 MB
    short* bufs = bufz + 8*(size_t)BUF_ELEMS;            // 33.5 MB
    short* xT   = bufs + 8*(size_t)BUF_ELEMS;            // 4 MB bf16 channel-last x
    short* Wt   = xT + BUF_ELEMS;                        // 1.33 MB bf16 weights (8 dirs)
    short* cont = Wt + 8*(size_t)WT_DIR;                 // 8 dirs x 4 MB bf16 contribs

    // Fused input/weight transposes (one dispatch).
    prep_xw<<<2048 + (8*WT_DIR + 255)/256, 256, 0, stream>>>(x, Wh, Wz, Ws, xT, Wt);

    // One conv dispatch for all 8 directions (one dir per block, M=256 tiles).
    conv_mfma<<<8*NB*DD*4, 256, 0, stream>>>(xT, Wt, bh, bz, bs, bufh, bufz, bufs);

    // One fused scan dispatch for all 8 directions (contribs into cont).
    gru_scan<<<dim3((2977 + 31)/32, NB, 8), 256, 0, stream>>>(bufh, bufz, bufs, cont, h0);

    // Sum dirs + transpose.
    transpose_out<<<NB*DD*DD, 256, 0, stream>>>(cont, out);
}